// Round 15
// baseline (702.885 us; speedup 1.0000x reference)
//
#include <hip/hip_runtime.h>
#include <hip/hip_bf16.h>

#define C_   512
#define HW_  4096
#define NTOK 8192
#define PZ_  16777216L   // Pexp batch stride (BYTES, fp8) in big mode

typedef __attribute__((ext_vector_type(8))) short bf16x8;
typedef __attribute__((ext_vector_type(4))) float f32x4;
typedef unsigned short u16;
typedef unsigned char u8;
typedef long i64;

#define MFMA16 __builtin_amdgcn_mfma_f32_16x16x32_bf16
#define MFMA8  __builtin_amdgcn_mfma_f32_16x16x32_fp8_fp8

__device__ __forceinline__ u16 f2bf(float f) {
  unsigned int u = __float_as_uint(f);
  u += 0x7fffu + ((u >> 16) & 1u);
  return (u16)(u >> 16);
}

// hardware packed f32->bf16 RNE (v_cvt_pk_bf16_f32)
__device__ __forceinline__ unsigned pk2(float a, float b) {
  __hip_bfloat162 h = __float22bfloat162_rn(make_float2(a, b));
  return *reinterpret_cast<unsigned*>(&h);
}

// hardware packed f32->fp8 e4m3 (v_cvt_pk_fp8_f32), 4 values -> u32
__device__ __forceinline__ unsigned pk4f8(float a, float b, float c, float d) {
  unsigned r = __builtin_amdgcn_cvt_pk_fp8_f32(a, b, 0u, false);
  return __builtin_amdgcn_cvt_pk_fp8_f32(c, d, r, true);
}

__device__ __forceinline__ float bf2f(u16 v) {
  return __uint_as_float((unsigned)v << 16);
}

__device__ __forceinline__ void gld_lds16(const void* g, void* l) {
  __builtin_amdgcn_global_load_lds(
      (const __attribute__((address_space(1))) void*)g,
      (__attribute__((address_space(3))) void*)l, 16, 0, 0);
}

// bf16 LDS swizzle (128-B rows, 8 chunks of 16B): chunk ^= row&7
__device__ __forceinline__ const u16* swz(const u16* base, int row, int col, int ldu16) {
  return base + (size_t)row * ldu16 + ((((col >> 3) ^ (row & 7)) << 3) | (col & 7));
}

// fp8 LDS tile [128 rows][64 B], 4 chunks of 16B/row: chunk ^= (row>>1)&3.
// frag addr for (row, kk-half h, lq): chunk = h*2+(lq>>1), within = (lq&1)*8.
// 2-way bank aliasing is the floor for 64-B rows (16-B staging granularity).
__device__ __forceinline__ const i64* swz8(const u8* base, int row, int h, int lq) {
  const int chunk = (h * 2 + (lq >> 1)) ^ ((row >> 1) & 3);
  return (const i64*)(base + row * 64 + (chunk << 4) + (lq & 1) * 8);
}

// K-PERMUTED STORAGE (within each 64-wide K group, logical col g*64+f*16+r
// stored at g*64+r*4+f). Consumers pair operands positionally -> MFMA
// k-reductions unaffected. Applied to qk/Pexp/vm (fp8), Op/ao/wpb (bf16).
// hT8 / weight K-dims are written in NATURAL order by head/gn_apply (both
// sides natural -> consistent).

// ---------------- head: wcast (bid<1024) + gn_stats1 (bid>=1024) ------------
__global__ __launch_bounds__(256) void head_kernel(
    const float* __restrict__ qw, const float* __restrict__ kw,
    const float* __restrict__ vw, const float* __restrict__ pw,
    u8* __restrict__ w8, u16* __restrict__ wpb, const float* __restrict__ x,
    float* __restrict__ gpart) {
  const int bid = blockIdx.x;
  const int t = threadIdx.x;
  if (bid < 1024) {
    int gid = bid * 256 + t;
    int which = gid >> 16;
    const float* src = which == 0 ? qw : which == 1 ? kw : which == 2 ? vw : pw;
    int loc = (gid & 65535) * 4;
    float4 v = *(const float4*)(src + loc);
    if (which == 3) {
      // wpb: bf16, permute channel (col) dim to match ao's stored layout
      const int row = loc >> 9, c = loc & 511;
      const int g = c & ~63, f = (c >> 4) & 3, r0 = c & 15;
      u16* base = wpb + (size_t)row * 512 + g;
      base[(r0 + 0) * 4 + f] = f2bf(v.x);
      base[(r0 + 1) * 4 + f] = f2bf(v.y);
      base[(r0 + 2) * 4 + f] = f2bf(v.z);
      base[(r0 + 3) * 4 + f] = f2bf(v.w);
    } else {
      // wq/wk/wv: fp8, natural K order
      *(unsigned*)(w8 + (size_t)which * 262144 + loc) = pk4f8(v.x, v.y, v.z, v.w);
    }
    return;
  }
  const int gb = bid - 1024;          // 512 blocks: group = gb>>3, chunk = gb&7
  const float4* p = (const float4*)(x + (size_t)(gb >> 3) * 65536 + (gb & 7) * 8192);
  float s = 0.0f, ss = 0.0f;
  for (int i = t; i < 2048; i += 256) {
    float4 v = p[i];
    s  += v.x + v.y + v.z + v.w;
    ss += v.x * v.x + v.y * v.y + v.z * v.z + v.w * v.w;
  }
  #pragma unroll
  for (int m = 1; m < 64; m <<= 1) { s += __shfl_xor(s, m); ss += __shfl_xor(ss, m); }
  __shared__ float rs[4], rss[4];
  const int wv = t >> 6;
  if ((t & 63) == 0) { rs[wv] = s; rss[wv] = ss; }
  __syncthreads();
  if (t == 0) {
    gpart[gb * 2]     = rs[0] + rs[1] + rs[2] + rs[3];
    gpart[gb * 2 + 1] = rss[0] + rss[1] + rss[2] + rss[3];
  }
}

// ---------------- GN apply (stage2 folded) + transpose to hT8[8192][512] fp8 -
__global__ __launch_bounds__(256) void gn_apply_kernel(const float* __restrict__ x,
                                                       const float* __restrict__ gnw,
                                                       const float* __restrict__ gnb,
                                                       const float* __restrict__ gpart,
                                                       u8* __restrict__ hT8) {
  const int b = blockIdx.z, c0 = blockIdx.y * 64, hw0 = blockIdx.x * 64;
  const int t = threadIdx.x;
  __shared__ float tile[64][65];
  __shared__ float gmean[4], grstd[4];
  if (t < 4) {
    const int g = b * 32 + (c0 >> 4) + t;
    float s = 0.0f, ss = 0.0f;
    #pragma unroll
    for (int cch = 0; cch < 8; ++cch) {
      s  += gpart[(g * 8 + cch) * 2];
      ss += gpart[(g * 8 + cch) * 2 + 1];
    }
    float mean = s * (1.0f / 65536.0f);
    float var  = fmaxf(ss * (1.0f / 65536.0f) - mean * mean, 0.0f);
    gmean[t] = mean;
    grstd[t] = rsqrtf(var + 1e-6f);
  }
  __syncthreads();
  {
    const int tx = t & 63, ty = t >> 6;  // ty 0..3
    #pragma unroll
    for (int i = 0; i < 16; ++i) {
      int cl = ty * 16 + i;
      int c = c0 + cl;
      float val = x[((size_t)(b * C_ + c)) * HW_ + hw0 + tx];
      tile[cl][tx] = (val - gmean[cl >> 4]) * grstd[cl >> 4] * gnw[c] + gnb[c];
    }
  }
  __syncthreads();
  {
    const int cx = (t & 15) * 4, ty = t >> 4;  // ty 0..15, 4 channels/thread
    #pragma unroll
    for (int i = 0; i < 4; ++i) {
      int hwl = ty * 4 + i;
      *(unsigned*)&hT8[((size_t)(b * HW_ + hw0 + hwl)) * 512 + c0 + cx] =
          pk4f8(tile[cx][hwl], tile[cx + 1][hwl], tile[cx + 2][hwl], tile[cx + 3][hwl]);
    }
  }
}

// ---------------- merged QKV GEMM (fp8 in), fp8 K-permuted out --------------
// bid < 512: qk part -> qk[8192][1024] fp8. bid >= 512: v -> vm[512][8192] fp8.
__global__ __launch_bounds__(256, 4) void qkv_kernel(
    const u8* __restrict__ hT8, const u8* __restrict__ w8,
    const float* __restrict__ qb, const float* __restrict__ kb,
    const float* __restrict__ vb,
    u8* __restrict__ qk, u8* __restrict__ vm)
{
  const int bid = blockIdx.x;
  const int t = threadIdx.x;
  const int wv = t >> 6, l = t & 63, lr = l & 15, lq = l >> 4;
  const int wr = wv >> 1, wc = wv & 1;       // 2x2 waves of 64x64
  const bool isqk = bid < 512;
  const int m0 = isqk ? (bid >> 3) * 128 : ((bid - 512) >> 6) * 128;
  const int n0 = isqk ? (bid & 7) * 128  : ((bid - 512) & 63) * 128;
  const u8* Arow = (isqk ? hT8 : w8 + 524288) + (size_t)m0 * 512;
  const u8* Brow = (isqk ? w8 : hT8) + (size_t)n0 * 512;
  __shared__ u8 As[8192];
  __shared__ u8 Bs[8192];
  f32x4 acc[4][4] = {};
  for (int k0 = 0; k0 < 512; k0 += 64) {
    #pragma unroll
    for (int it = 0; it < 2; ++it) {
      const int ci = it * 256 + t;           // 512 chunks of 16B per tile
      const int row = ci >> 2;
      const int src = (((ci & 3) ^ ((row >> 1) & 3)) << 4);
      gld_lds16(Arow + (size_t)row * 512 + k0 + src, As + ci * 16);
      gld_lds16(Brow + (size_t)row * 512 + k0 + src, Bs + ci * 16);
    }
    __syncthreads();
    #pragma unroll
    for (int h = 0; h < 2; ++h) {
      i64 af[4], bf[4];
      #pragma unroll
      for (int fr = 0; fr < 4; ++fr)
        af[fr] = *swz8(As, wr * 64 + fr * 16 + lr, h, lq);
      #pragma unroll
      for (int fc = 0; fc < 4; ++fc)
        bf[fc] = *swz8(Bs, wc * 64 + fc * 16 + lr, h, lq);
      #pragma unroll
      for (int fr = 0; fr < 4; ++fr)
        #pragma unroll
        for (int fc = 0; fc < 4; ++fc)
          acc[fr][fc] = MFMA8(af[fr], bf[fc], acc[fr][fc], 0, 0, 0);
    }
    __syncthreads();
  }
  if (isqk) {
    float bn[4];
    #pragma unroll
    for (int fc = 0; fc < 4; ++fc) {
      const int n = n0 + wc * 64 + fc * 16 + lr;     // logical col for bias
      bn[fc] = n < 512 ? qb[n] : kb[n - 512];
    }
    #pragma unroll
    for (int fr = 0; fr < 4; ++fr) {
      #pragma unroll
      for (int reg = 0; reg < 4; ++reg) {
        const int m = m0 + wr * 64 + fr * 16 + lq * 4 + reg;
        *(unsigned*)(qk + (size_t)m * 1024 + n0 + wc * 64 + lr * 4) =
            pk4f8(acc[fr][0][reg] + bn[0], acc[fr][1][reg] + bn[1],
                  acc[fr][2][reg] + bn[2], acc[fr][3][reg] + bn[3]);
      }
    }
  } else {
    #pragma unroll
    for (int fr = 0; fr < 4; ++fr) {
      #pragma unroll
      for (int reg = 0; reg < 4; ++reg) {
        const int m = m0 + wr * 64 + fr * 16 + lq * 4 + reg;
        const float bm = vb[m];
        *(unsigned*)(vm + (size_t)m * NTOK + n0 + wc * 64 + lr * 4) =
            pk4f8(acc[fr][0][reg] + bm, acc[fr][1][reg] + bm,
                  acc[fr][2][reg] + bm, acc[fr][3][reg] + bm);
      }
    }
  }
}

// ---------------- S-GEMM fp8 + exp + rowsum partials -------------------------
// A,B = qk fp8 slices (row stride 1024 B). Pexp fp8, K-permuted cols.
__global__ __launch_bounds__(256, 8) void sgemm_exp_kernel(
    const u8* __restrict__ A, const u8* __restrict__ B,
    u8* __restrict__ Pexp, float* __restrict__ rsp, long pz, int gi0base)
{
  const int z = blockIdx.z;
  A    += (size_t)z * (HW_ * 1024);
  B    += (size_t)z * (HW_ * 1024);
  Pexp += (size_t)z * pz;
  const int gi0 = gi0base + z * HW_;
  const int t = threadIdx.x;
  const int m0 = blockIdx.x * 128, n0 = blockIdx.y * 128;
  const int wv = t >> 6, l = t & 63, lr = l & 15, lq = l >> 4;
  const int wr = wv >> 1, wc = wv & 1;       // 2x2 waves of 64x64
  __shared__ u8 As[8192];                    // [128][64] fp8, swizzled
  __shared__ u8 Bs[8192];
  f32x4 acc[4][4] = {};
  for (int k0 = 0; k0 < 512; k0 += 64) {
    #pragma unroll
    for (int it = 0; it < 2; ++it) {
      const int ci = it * 256 + t;           // 512 chunks of 16B per tile
      const int row = ci >> 2;
      const int src = (((ci & 3) ^ ((row >> 1) & 3)) << 4);
      gld_lds16(A + (size_t)(m0 + row) * 1024 + k0 + src, As + ci * 16);
      gld_lds16(B + (size_t)(n0 + row) * 1024 + k0 + src, Bs + ci * 16);
    }
    __syncthreads();
    #pragma unroll
    for (int h = 0; h < 2; ++h) {
      i64 af[4], bf[4];
      #pragma unroll
      for (int fr = 0; fr < 4; ++fr)
        af[fr] = *swz8(As, wr * 64 + fr * 16 + lr, h, lq);
      #pragma unroll
      for (int fc = 0; fc < 4; ++fc)
        bf[fc] = *swz8(Bs, wc * 64 + fc * 16 + lr, h, lq);
      #pragma unroll
      for (int fr = 0; fr < 4; ++fr)
        #pragma unroll
        for (int fc = 0; fc < 4; ++fc)
          acc[fr][fc] = MFMA8(af[fr], bf[fc], acc[fr][fc], 0, 0, 0);
    }
    __syncthreads();
  }
  const float SCL2 = 0.06376774487989831f;   // log2(e)/sqrt(512)
  #pragma unroll
  for (int fr = 0; fr < 4; ++fr) {
    #pragma unroll
    for (int reg = 0; reg < 4; ++reg) {
      const int row = m0 + wr * 64 + fr * 16 + lq * 4 + reg;
      float p0 = exp2f(acc[fr][0][reg] * SCL2 - 1.0f);
      float p1 = exp2f(acc[fr][1][reg] * SCL2 - 1.0f);
      float p2 = exp2f(acc[fr][2][reg] * SCL2 - 1.0f);
      float p3 = exp2f(acc[fr][3][reg] * SCL2 - 1.0f);
      float rsum = p0 + p1 + p2 + p3;
      *(unsigned*)(Pexp + (size_t)row * 4096 + n0 + wc * 64 + lr * 4) =
          pk4f8(p0, p1, p2, p3);
      rsum += __shfl_xor(rsum, 1);
      rsum += __shfl_xor(rsum, 2);
      rsum += __shfl_xor(rsum, 4);
      rsum += __shfl_xor(rsum, 8);
      if (lr == 0)
        rsp[(size_t)(blockIdx.y * 2 + wc) * NTOK + gi0 + row] = rsum;
    }
  }
}

// ---------------- PV GEMM fp8 split-K, 128x128 tile --------------------------
// A=Pexp fp8 (row 4096 B), B=vm fp8 (row 8192 B). Op bf16, K-permuted ch.
__global__ __launch_bounds__(256, 8) void pvgemm_splitk(
    const u8* __restrict__ A, const u8* __restrict__ B,
    u16* __restrict__ Op, long spstride, int logsplit)
{
  const int z = blockIdx.z;
  const int sp = z & ((1 << logsplit) - 1);
  const int bb = z >> logsplit;
  A  += (size_t)bb * PZ_;
  B  += (size_t)bb * HW_;
  Op += (size_t)sp * spstride + (size_t)bb * 2097152;
  const int t = threadIdx.x;
  const int m0 = blockIdx.x * 128, n0 = blockIdx.y * 128;
  const int wv = t >> 6, l = t & 63, lr = l & 15, lq = l >> 4;
  const int wr = wv >> 1, wc = wv & 1;       // 2x2 waves of 64x64
  __shared__ u8 As[8192];
  __shared__ u8 Bs[8192];
  f32x4 acc[4][4] = {};
  const int ksize = 4096 >> logsplit;
  const int kbeg = sp * ksize;
  for (int k0 = kbeg; k0 < kbeg + ksize; k0 += 64) {
    #pragma unroll
    for (int it = 0; it < 2; ++it) {
      const int ci = it * 256 + t;           // 512 chunks per tile
      const int row = ci >> 2;
      const int src = (((ci & 3) ^ ((row >> 1) & 3)) << 4);
      gld_lds16(A + (size_t)(m0 + row) * 4096 + k0 + src, As + ci * 16);
      gld_lds16(B + (size_t)(n0 + row) * NTOK + k0 + src, Bs + ci * 16);
    }
    __syncthreads();
    #pragma unroll
    for (int h = 0; h < 2; ++h) {
      i64 af[4], bf[4];
      #pragma unroll
      for (int fr = 0; fr < 4; ++fr)
        af[fr] = *swz8(As, wr * 64 + fr * 16 + lr, h, lq);
      #pragma unroll
      for (int fc = 0; fc < 4; ++fc)
        bf[fc] = *swz8(Bs, wc * 64 + fc * 16 + lr, h, lq);
      #pragma unroll
      for (int fr = 0; fr < 4; ++fr)
        #pragma unroll
        for (int fc = 0; fc < 4; ++fc)
          acc[fr][fc] = MFMA8(af[fr], bf[fc], acc[fr][fc], 0, 0, 0);
    }
    __syncthreads();
  }
  #pragma unroll
  for (int fr = 0; fr < 4; ++fr) {
    #pragma unroll
    for (int reg = 0; reg < 4; ++reg) {
      const int m = m0 + wr * 64 + fr * 16 + lq * 4 + reg;
      uint2 o;
      o.x = pk2(acc[fr][0][reg], acc[fr][1][reg]);
      o.y = pk2(acc[fr][2][reg], acc[fr][3][reg]);
      *(uint2*)(Op + (size_t)m * 512 + n0 + wc * 64 + lr * 4) = o;
    }
  }
}

// ---------------- combine split-K partials + rowsum-normalize (folded) ------
__global__ __launch_bounds__(256) void combine_norm(const u16* __restrict__ Op,
                                                    const float* __restrict__ rsp,
                                                    u16* __restrict__ ao,
                                                    long spstride, int nsplit, int gi0) {
  const int t = threadIdx.x;
  __shared__ float rinvs[4];
  {
    const int tokl = t >> 6, jg = t & 63;
    float s = rsp[(size_t)jg * NTOK + gi0 + blockIdx.x * 4 + tokl];
    #pragma unroll
    for (int m = 1; m < 64; m <<= 1) s += __shfl_xor(s, m);
    if (jg == 0) rinvs[tokl] = 1.0f / s;
  }
  __syncthreads();
  const size_t idx8 = ((size_t)blockIdx.x * 256 + t) * 8;
  const float ri = rinvs[t >> 6];
  float v[8] = {};
  for (int s = 0; s < nsplit; ++s) {
    const u16* p = Op + (size_t)s * spstride + idx8;
    ushort4 a0 = *(const ushort4*)p;
    ushort4 a1 = *(const ushort4*)(p + 4);
    v[0] += bf2f(a0.x); v[1] += bf2f(a0.y); v[2] += bf2f(a0.z); v[3] += bf2f(a0.w);
    v[4] += bf2f(a1.x); v[5] += bf2f(a1.y); v[6] += bf2f(a1.z); v[7] += bf2f(a1.w);
  }
  uint2 o0, o1;
  o0.x = pk2(v[0] * ri, v[1] * ri);
  o0.y = pk2(v[2] * ri, v[3] * ri);
  o1.x = pk2(v[4] * ri, v[5] * ri);
  o1.y = pk2(v[6] * ri, v[7] * ri);
  *(uint2*)(ao + idx8)     = o0;
  *(uint2*)(ao + idx8 + 4) = o1;
}

// ---------------- proj GEMM (bf16), 128x128 tile + bias + fp32 residual -----
__global__ __launch_bounds__(256, 4) void projgemm_kernel(
    const u16* __restrict__ A, const u16* __restrict__ B,
    const float* __restrict__ bias, const float* __restrict__ resid,
    float* __restrict__ D)
{
  const int z = blockIdx.z;
  B     += (size_t)z * 2097152;
  resid += (size_t)z * 2097152;
  D     += (size_t)z * 2097152;
  const int t = threadIdx.x;
  const int m0 = blockIdx.x * 128, n0 = blockIdx.y * 128;
  const int wv = t >> 6, l = t & 63, lr = l & 15, lq = l >> 4;
  const int wr = wv >> 1, wc = wv & 1;       // 2x2 waves of 64x64
  __shared__ u16 As[128][64];
  __shared__ u16 Bs[128][64];
  f32x4 acc[4][4] = {};
  for (int k0 = 0; k0 < 512; k0 += 64) {
    #pragma unroll
    for (int it = 0; it < 4; ++it) {
      const int ci = it * 256 + t;           // 1024 chunks of 16B
      const int row = ci >> 3;
      const int c8 = (((ci & 7) ^ (row & 7)) << 3);  // inverse-swizzled src octet
      gld_lds16(A + (size_t)(m0 + row) * 512 + k0 + c8, &As[0][0] + ci * 8);
      gld_lds16(B + (size_t)(n0 + row) * 512 + k0 + c8, &Bs[0][0] + ci * 8);
    }
    __syncthreads();
    #pragma unroll
    for (int kk = 0; kk < 64; kk += 32) {
      bf16x8 af[4], bf[4];
      #pragma unroll
      for (int fr = 0; fr < 4; ++fr)
        af[fr] = *(const bf16x8*)swz(&As[0][0], wr * 64 + fr * 16 + lr, kk + lq * 8, 64);
      #pragma unroll
      for (int fc = 0; fc < 4; ++fc)
        bf[fc] = *(const bf16x8*)swz(&Bs[0][0], wc * 64 + fc * 16 + lr, kk + lq * 8, 64);
      #pragma unroll
      for (int fr = 0; fr < 4; ++fr)
        #pragma unroll
        for (int fc = 0; fc < 4; ++fc)
          acc[fr][fc] = MFMA16(af[fr], bf[fc], acc[fr][fc], 0, 0, 0);
    }
    __syncthreads();
  }
  #pragma unroll
  for (int fr = 0; fr < 4; ++fr) {
    #pragma unroll
    for (int reg = 0; reg < 4; ++reg) {
      const int m = m0 + wr * 64 + fr * 16 + lq * 4 + reg;
      const float bm = bias[m];
      #pragma unroll
      for (int fc = 0; fc < 4; ++fc) {
        const int n = n0 + wc * 64 + fc * 16 + lr;
        const size_t idx = (size_t)m * HW_ + n;
        D[idx] = acc[fr][fc][reg] + bm + resid[idx];
      }
    }
  }
}

extern "C" void kernel_launch(void* const* d_in, const int* in_sizes, int n_in,
                              void* d_out, int out_size, void* d_ws, size_t ws_size,
                              hipStream_t stream) {
  const float* x   = (const float*)d_in[0];
  const float* gnw = (const float*)d_in[1];
  const float* gnb = (const float*)d_in[2];
  const float* qw  = (const float*)d_in[3];
  const float* qb  = (const float*)d_in[4];
  const float* kw  = (const float*)d_in[5];
  const float* kb  = (const float*)d_in[6];
  const float* vw  = (const float*)d_in[7];
  const float* vb  = (const float*)d_in[8];
  const float* pw  = (const float*)d_in[9];
  const float* pb  = (const float*)d_in[10];

  // common prefix layout (both modes)
  char* ws = (char*)d_ws;
  u8*    w8    = (u8*)(ws + 0);              // wq|wk fp8 [1024][512B], wv fp8 [512][512B]
  u16*   wpb   = (u16*)(ws + 786432);        // [512][512] bf16, col dim K-permuted
  float* rsp   = (float*)(ws + 2130432);     // [64][8192] f32 (2MB)
  float* gpart = rsp;                        // gn partials alias rsp (pre-sgemm)
  u8*    hT8   = (u8*)(ws + 4227584);        // [8192][512] fp8 (4MB), dead after qkv
  u16*   ao    = (u16*)(ws + 4227584);       // reuse: [2][4096][512] bf16 (8MB, K-perm ch)
  u8*    qk    = (u8*)(ws + 12616192);       // [8192][1024] fp8 (q|k, K-permuted)
  u8*    vm    = (u8*)(ws + 29393408);       // [512][8192] fp8 (K-permuted tokens)

  // big mode: 8-way split-K bf16 Op partials + both-batch fp8 Pexp
  const bool big = ws_size >= 138445312ULL;
  u16* OpB   = (u16*)(ws + 37782016);        // [8][2][4096][512] bf16 (67MB)
  u8*  PexpB = (u8*)(ws + 104890880);        // [2][4096][4096] fp8 (33.5MB)
  // fallback (ws >= 77.66MB proven): single-batch fp8 Pexp + 2-way Op
  u8*  PexpS = (u8*)(ws + 37782016);         // [4096][4096] fp8 (16.8MB)
  u16* OpS   = (u16*)(ws + 54559232);        // [2][4096][512] bf16 (8MB)

  head_kernel<<<1536, 256, 0, stream>>>(qw, kw, vw, pw, w8, wpb, x, gpart);
  gn_apply_kernel<<<dim3(64, 8, 2), 256, 0, stream>>>(x, gnw, gnb, gpart, hT8);
  // merged q+k (512 blocks) and v (256 blocks) in one dispatch
  qkv_kernel<<<768, 256, 0, stream>>>(hT8, w8, qb, kb, vb, qk, vm);

  if (big) {
    sgemm_exp_kernel<<<dim3(32, 32, 2), 256, 0, stream>>>(qk, qk + 512, PexpB, rsp, PZ_, 0);
    pvgemm_splitk<<<dim3(32, 4, 16), 256, 0, stream>>>(PexpB, vm, OpB, 4194304L, 3);
    combine_norm<<<2048, 256, 0, stream>>>(OpB, rsp, ao, 4194304L, 8, 0);
  } else {
    for (int b = 0; b < 2; ++b) {
      const u8* qkb = qk + (size_t)b * HW_ * 1024;
      sgemm_exp_kernel<<<dim3(32, 32, 1), 256, 0, stream>>>(qkb, qkb + 512, PexpS, rsp, 0L, b * HW_);
      pvgemm_splitk<<<dim3(32, 4, 2), 256, 0, stream>>>(PexpS, vm + (size_t)b * HW_, OpS, 2097152L, 1);
      combine_norm<<<1024, 256, 0, stream>>>(OpS, rsp, ao + (size_t)b * HW_ * C_, 2097152L, 2, b * HW_);
    }
  }
  // proj + bias + residual: A=wpb (cols K-permuted), B=ao (cols K-permuted)
  projgemm_kernel<<<dim3(4, 32, 2), 256, 0, stream>>>(wpb, ao, pb, x, (float*)d_out);
}

// Round 16
// 117.771 us; speedup vs baseline: 5.9682x; 5.9682x over previous
//
#include <hip/hip_runtime.h>
#include <hip/hip_bf16.h>

#define C_   512
#define HW_  4096
#define NTOK 8192
#define PZ_  16777216L   // Pexp batch stride (BYTES, fp8) in big mode

typedef __attribute__((ext_vector_type(8))) short bf16x8;
typedef __attribute__((ext_vector_type(4))) float f32x4;
typedef unsigned short u16;
typedef unsigned char u8;
typedef long i64;

#define MFMA16 __builtin_amdgcn_mfma_f32_16x16x32_bf16
#define MFMA8  __builtin_amdgcn_mfma_f32_16x16x32_fp8_fp8

__device__ __forceinline__ u16 f2bf(float f) {
  unsigned int u = __float_as_uint(f);
  u += 0x7fffu + ((u >> 16) & 1u);
  return (u16)(u >> 16);
}

// hardware packed f32->bf16 RNE (v_cvt_pk_bf16_f32)
__device__ __forceinline__ unsigned pk2(float a, float b) {
  __hip_bfloat162 h = __float22bfloat162_rn(make_float2(a, b));
  return *reinterpret_cast<unsigned*>(&h);
}

// hardware packed f32->fp8 e4m3 (v_cvt_pk_fp8_f32), 4 values -> u32
__device__ __forceinline__ unsigned pk4f8(float a, float b, float c, float d) {
  unsigned r = __builtin_amdgcn_cvt_pk_fp8_f32(a, b, 0u, false);
  return __builtin_amdgcn_cvt_pk_fp8_f32(c, d, r, true);
}

__device__ __forceinline__ float bf2f(u16 v) {
  return __uint_as_float((unsigned)v << 16);
}

__device__ __forceinline__ void gld_lds16(const void* g, void* l) {
  __builtin_amdgcn_global_load_lds(
      (const __attribute__((address_space(1))) void*)g,
      (__attribute__((address_space(3))) void*)l, 16, 0, 0);
}

// bf16 LDS swizzle (128-B rows, 8 chunks of 16B): chunk ^= row&7
__device__ __forceinline__ const u16* swz(const u16* base, int row, int col, int ldu16) {
  return base + (size_t)row * ldu16 + ((((col >> 3) ^ (row & 7)) << 3) | (col & 7));
}

// fp8 LDS tile [128 rows][64 B], 4 chunks of 16B/row: chunk ^= (row>>1)&3.
// frag addr for (row, kk-half h, lq): chunk = h*2+(lq>>1), within = (lq&1)*8.
// 2-way bank aliasing is the floor for 64-B rows (16-B staging granularity).
__device__ __forceinline__ const i64* swz8(const u8* base, int row, int h, int lq) {
  const int chunk = (h * 2 + (lq >> 1)) ^ ((row >> 1) & 3);
  return (const i64*)(base + row * 64 + (chunk << 4) + (lq & 1) * 8);
}

// K-PERMUTED STORAGE (within each 64-wide K group, logical col g*64+f*16+r
// stored at g*64+r*4+f). Consumers pair operands positionally -> MFMA
// k-reductions unaffected. Applied to qk/Pexp/vm (fp8), Op/ao/wpb (bf16).
// hT8 / weight K-dims are written in NATURAL order by head/gn_apply (both
// sides natural -> consistent).
//
// LAUNCH_BOUNDS NOTE (R15 post-mortem): (256,8) caps VGPR at 64 -> the
// 128^2 GEMM body (acc 64 + frags + addressing ~80) SPILLS to scratch
// (VGPR_Count=32, FETCH 533MB, 10x slowdown). Keep (256,4) = 128-VGPR cap.

// ---------------- head: wcast (bid<1024) + gn_stats1 (bid>=1024) ------------
__global__ __launch_bounds__(256) void head_kernel(
    const float* __restrict__ qw, const float* __restrict__ kw,
    const float* __restrict__ vw, const float* __restrict__ pw,
    u8* __restrict__ w8, u16* __restrict__ wpb, const float* __restrict__ x,
    float* __restrict__ gpart) {
  const int bid = blockIdx.x;
  const int t = threadIdx.x;
  if (bid < 1024) {
    int gid = bid * 256 + t;
    int which = gid >> 16;
    const float* src = which == 0 ? qw : which == 1 ? kw : which == 2 ? vw : pw;
    int loc = (gid & 65535) * 4;
    float4 v = *(const float4*)(src + loc);
    if (which == 3) {
      // wpb: bf16, permute channel (col) dim to match ao's stored layout
      const int row = loc >> 9, c = loc & 511;
      const int g = c & ~63, f = (c >> 4) & 3, r0 = c & 15;
      u16* base = wpb + (size_t)row * 512 + g;
      base[(r0 + 0) * 4 + f] = f2bf(v.x);
      base[(r0 + 1) * 4 + f] = f2bf(v.y);
      base[(r0 + 2) * 4 + f] = f2bf(v.z);
      base[(r0 + 3) * 4 + f] = f2bf(v.w);
    } else {
      // wq/wk/wv: fp8, natural K order
      *(unsigned*)(w8 + (size_t)which * 262144 + loc) = pk4f8(v.x, v.y, v.z, v.w);
    }
    return;
  }
  const int gb = bid - 1024;          // 512 blocks: group = gb>>3, chunk = gb&7
  const float4* p = (const float4*)(x + (size_t)(gb >> 3) * 65536 + (gb & 7) * 8192);
  float s = 0.0f, ss = 0.0f;
  for (int i = t; i < 2048; i += 256) {
    float4 v = p[i];
    s  += v.x + v.y + v.z + v.w;
    ss += v.x * v.x + v.y * v.y + v.z * v.z + v.w * v.w;
  }
  #pragma unroll
  for (int m = 1; m < 64; m <<= 1) { s += __shfl_xor(s, m); ss += __shfl_xor(ss, m); }
  __shared__ float rs[4], rss[4];
  const int wv = t >> 6;
  if ((t & 63) == 0) { rs[wv] = s; rss[wv] = ss; }
  __syncthreads();
  if (t == 0) {
    gpart[gb * 2]     = rs[0] + rs[1] + rs[2] + rs[3];
    gpart[gb * 2 + 1] = rss[0] + rss[1] + rss[2] + rss[3];
  }
}

// ---------------- GN apply (stage2 folded) + transpose to hT8[8192][512] fp8 -
__global__ __launch_bounds__(256) void gn_apply_kernel(const float* __restrict__ x,
                                                       const float* __restrict__ gnw,
                                                       const float* __restrict__ gnb,
                                                       const float* __restrict__ gpart,
                                                       u8* __restrict__ hT8) {
  const int b = blockIdx.z, c0 = blockIdx.y * 64, hw0 = blockIdx.x * 64;
  const int t = threadIdx.x;
  __shared__ float tile[64][65];
  __shared__ float gmean[4], grstd[4];
  if (t < 4) {
    const int g = b * 32 + (c0 >> 4) + t;
    float s = 0.0f, ss = 0.0f;
    #pragma unroll
    for (int cch = 0; cch < 8; ++cch) {
      s  += gpart[(g * 8 + cch) * 2];
      ss += gpart[(g * 8 + cch) * 2 + 1];
    }
    float mean = s * (1.0f / 65536.0f);
    float var  = fmaxf(ss * (1.0f / 65536.0f) - mean * mean, 0.0f);
    gmean[t] = mean;
    grstd[t] = rsqrtf(var + 1e-6f);
  }
  __syncthreads();
  {
    const int tx = t & 63, ty = t >> 6;  // ty 0..3
    #pragma unroll
    for (int i = 0; i < 16; ++i) {
      int cl = ty * 16 + i;
      int c = c0 + cl;
      float val = x[((size_t)(b * C_ + c)) * HW_ + hw0 + tx];
      tile[cl][tx] = (val - gmean[cl >> 4]) * grstd[cl >> 4] * gnw[c] + gnb[c];
    }
  }
  __syncthreads();
  {
    const int cx = (t & 15) * 4, ty = t >> 4;  // ty 0..15, 4 channels/thread
    #pragma unroll
    for (int i = 0; i < 4; ++i) {
      int hwl = ty * 4 + i;
      *(unsigned*)&hT8[((size_t)(b * HW_ + hw0 + hwl)) * 512 + c0 + cx] =
          pk4f8(tile[cx][hwl], tile[cx + 1][hwl], tile[cx + 2][hwl], tile[cx + 3][hwl]);
    }
  }
}

// ---------------- merged QKV GEMM (fp8 in), fp8 K-permuted out --------------
// bid < 512: qk part -> qk[8192][1024] fp8. bid >= 512: v -> vm[512][8192] fp8.
__global__ __launch_bounds__(256, 4) void qkv_kernel(
    const u8* __restrict__ hT8, const u8* __restrict__ w8,
    const float* __restrict__ qb, const float* __restrict__ kb,
    const float* __restrict__ vb,
    u8* __restrict__ qk, u8* __restrict__ vm)
{
  const int bid = blockIdx.x;
  const int t = threadIdx.x;
  const int wv = t >> 6, l = t & 63, lr = l & 15, lq = l >> 4;
  const int wr = wv >> 1, wc = wv & 1;       // 2x2 waves of 64x64
  const bool isqk = bid < 512;
  const int m0 = isqk ? (bid >> 3) * 128 : ((bid - 512) >> 6) * 128;
  const int n0 = isqk ? (bid & 7) * 128  : ((bid - 512) & 63) * 128;
  const u8* Arow = (isqk ? hT8 : w8 + 524288) + (size_t)m0 * 512;
  const u8* Brow = (isqk ? w8 : hT8) + (size_t)n0 * 512;
  __shared__ u8 As[8192];
  __shared__ u8 Bs[8192];
  f32x4 acc[4][4] = {};
  for (int k0 = 0; k0 < 512; k0 += 64) {
    #pragma unroll
    for (int it = 0; it < 2; ++it) {
      const int ci = it * 256 + t;           // 512 chunks of 16B per tile
      const int row = ci >> 2;
      const int src = (((ci & 3) ^ ((row >> 1) & 3)) << 4);
      gld_lds16(Arow + (size_t)row * 512 + k0 + src, As + ci * 16);
      gld_lds16(Brow + (size_t)row * 512 + k0 + src, Bs + ci * 16);
    }
    __syncthreads();
    #pragma unroll
    for (int h = 0; h < 2; ++h) {
      i64 af[4], bf[4];
      #pragma unroll
      for (int fr = 0; fr < 4; ++fr)
        af[fr] = *swz8(As, wr * 64 + fr * 16 + lr, h, lq);
      #pragma unroll
      for (int fc = 0; fc < 4; ++fc)
        bf[fc] = *swz8(Bs, wc * 64 + fc * 16 + lr, h, lq);
      #pragma unroll
      for (int fr = 0; fr < 4; ++fr)
        #pragma unroll
        for (int fc = 0; fc < 4; ++fc)
          acc[fr][fc] = MFMA8(af[fr], bf[fc], acc[fr][fc], 0, 0, 0);
    }
    __syncthreads();
  }
  if (isqk) {
    float bn[4];
    #pragma unroll
    for (int fc = 0; fc < 4; ++fc) {
      const int n = n0 + wc * 64 + fc * 16 + lr;     // logical col for bias
      bn[fc] = n < 512 ? qb[n] : kb[n - 512];
    }
    #pragma unroll
    for (int fr = 0; fr < 4; ++fr) {
      #pragma unroll
      for (int reg = 0; reg < 4; ++reg) {
        const int m = m0 + wr * 64 + fr * 16 + lq * 4 + reg;
        *(unsigned*)(qk + (size_t)m * 1024 + n0 + wc * 64 + lr * 4) =
            pk4f8(acc[fr][0][reg] + bn[0], acc[fr][1][reg] + bn[1],
                  acc[fr][2][reg] + bn[2], acc[fr][3][reg] + bn[3]);
      }
    }
  } else {
    #pragma unroll
    for (int fr = 0; fr < 4; ++fr) {
      #pragma unroll
      for (int reg = 0; reg < 4; ++reg) {
        const int m = m0 + wr * 64 + fr * 16 + lq * 4 + reg;
        const float bm = vb[m];
        *(unsigned*)(vm + (size_t)m * NTOK + n0 + wc * 64 + lr * 4) =
            pk4f8(acc[fr][0][reg] + bm, acc[fr][1][reg] + bm,
                  acc[fr][2][reg] + bm, acc[fr][3][reg] + bm);
      }
    }
  }
}

// ---------------- S-GEMM fp8 + exp + rowsum partials -------------------------
// A,B = qk fp8 slices (row stride 1024 B). Pexp fp8, K-permuted cols.
__global__ __launch_bounds__(256, 4) void sgemm_exp_kernel(
    const u8* __restrict__ A, const u8* __restrict__ B,
    u8* __restrict__ Pexp, float* __restrict__ rsp, long pz, int gi0base)
{
  const int z = blockIdx.z;
  A    += (size_t)z * (HW_ * 1024);
  B    += (size_t)z * (HW_ * 1024);
  Pexp += (size_t)z * pz;
  const int gi0 = gi0base + z * HW_;
  const int t = threadIdx.x;
  const int m0 = blockIdx.x * 128, n0 = blockIdx.y * 128;
  const int wv = t >> 6, l = t & 63, lr = l & 15, lq = l >> 4;
  const int wr = wv >> 1, wc = wv & 1;       // 2x2 waves of 64x64
  __shared__ u8 As[8192];                    // [128][64] fp8, swizzled
  __shared__ u8 Bs[8192];
  f32x4 acc[4][4] = {};
  for (int k0 = 0; k0 < 512; k0 += 64) {
    #pragma unroll
    for (int it = 0; it < 2; ++it) {
      const int ci = it * 256 + t;           // 512 chunks of 16B per tile
      const int row = ci >> 2;
      const int src = (((ci & 3) ^ ((row >> 1) & 3)) << 4);
      gld_lds16(A + (size_t)(m0 + row) * 1024 + k0 + src, As + ci * 16);
      gld_lds16(B + (size_t)(n0 + row) * 1024 + k0 + src, Bs + ci * 16);
    }
    __syncthreads();
    #pragma unroll
    for (int h = 0; h < 2; ++h) {
      i64 af[4], bf[4];
      #pragma unroll
      for (int fr = 0; fr < 4; ++fr)
        af[fr] = *swz8(As, wr * 64 + fr * 16 + lr, h, lq);
      #pragma unroll
      for (int fc = 0; fc < 4; ++fc)
        bf[fc] = *swz8(Bs, wc * 64 + fc * 16 + lr, h, lq);
      #pragma unroll
      for (int fr = 0; fr < 4; ++fr)
        #pragma unroll
        for (int fc = 0; fc < 4; ++fc)
          acc[fr][fc] = MFMA8(af[fr], bf[fc], acc[fr][fc], 0, 0, 0);
    }
    __syncthreads();
  }
  const float SCL2 = 0.06376774487989831f;   // log2(e)/sqrt(512)
  #pragma unroll
  for (int fr = 0; fr < 4; ++fr) {
    #pragma unroll
    for (int reg = 0; reg < 4; ++reg) {
      const int row = m0 + wr * 64 + fr * 16 + lq * 4 + reg;
      float p0 = exp2f(acc[fr][0][reg] * SCL2 - 1.0f);
      float p1 = exp2f(acc[fr][1][reg] * SCL2 - 1.0f);
      float p2 = exp2f(acc[fr][2][reg] * SCL2 - 1.0f);
      float p3 = exp2f(acc[fr][3][reg] * SCL2 - 1.0f);
      float rsum = p0 + p1 + p2 + p3;
      *(unsigned*)(Pexp + (size_t)row * 4096 + n0 + wc * 64 + lr * 4) =
          pk4f8(p0, p1, p2, p3);
      rsum += __shfl_xor(rsum, 1);
      rsum += __shfl_xor(rsum, 2);
      rsum += __shfl_xor(rsum, 4);
      rsum += __shfl_xor(rsum, 8);
      if (lr == 0)
        rsp[(size_t)(blockIdx.y * 2 + wc) * NTOK + gi0 + row] = rsum;
    }
  }
}

// ---------------- PV GEMM fp8 split-K, 128x128 tile --------------------------
// A=Pexp fp8 (row 4096 B), B=vm fp8 (row 8192 B). Op bf16, K-permuted ch.
__global__ __launch_bounds__(256, 4) void pvgemm_splitk(
    const u8* __restrict__ A, const u8* __restrict__ B,
    u16* __restrict__ Op, long spstride, int logsplit)
{
  const int z = blockIdx.z;
  const int sp = z & ((1 << logsplit) - 1);
  const int bb = z >> logsplit;
  A  += (size_t)bb * PZ_;
  B  += (size_t)bb * HW_;
  Op += (size_t)sp * spstride + (size_t)bb * 2097152;
  const int t = threadIdx.x;
  const int m0 = blockIdx.x * 128, n0 = blockIdx.y * 128;
  const int wv = t >> 6, l = t & 63, lr = l & 15, lq = l >> 4;
  const int wr = wv >> 1, wc = wv & 1;       // 2x2 waves of 64x64
  __shared__ u8 As[8192];
  __shared__ u8 Bs[8192];
  f32x4 acc[4][4] = {};
  const int ksize = 4096 >> logsplit;
  const int kbeg = sp * ksize;
  for (int k0 = kbeg; k0 < kbeg + ksize; k0 += 64) {
    #pragma unroll
    for (int it = 0; it < 2; ++it) {
      const int ci = it * 256 + t;           // 512 chunks per tile
      const int row = ci >> 2;
      const int src = (((ci & 3) ^ ((row >> 1) & 3)) << 4);
      gld_lds16(A + (size_t)(m0 + row) * 4096 + k0 + src, As + ci * 16);
      gld_lds16(B + (size_t)(n0 + row) * NTOK + k0 + src, Bs + ci * 16);
    }
    __syncthreads();
    #pragma unroll
    for (int h = 0; h < 2; ++h) {
      i64 af[4], bf[4];
      #pragma unroll
      for (int fr = 0; fr < 4; ++fr)
        af[fr] = *swz8(As, wr * 64 + fr * 16 + lr, h, lq);
      #pragma unroll
      for (int fc = 0; fc < 4; ++fc)
        bf[fc] = *swz8(Bs, wc * 64 + fc * 16 + lr, h, lq);
      #pragma unroll
      for (int fr = 0; fr < 4; ++fr)
        #pragma unroll
        for (int fc = 0; fc < 4; ++fc)
          acc[fr][fc] = MFMA8(af[fr], bf[fc], acc[fr][fc], 0, 0, 0);
    }
    __syncthreads();
  }
  #pragma unroll
  for (int fr = 0; fr < 4; ++fr) {
    #pragma unroll
    for (int reg = 0; reg < 4; ++reg) {
      const int m = m0 + wr * 64 + fr * 16 + lq * 4 + reg;
      uint2 o;
      o.x = pk2(acc[fr][0][reg], acc[fr][1][reg]);
      o.y = pk2(acc[fr][2][reg], acc[fr][3][reg]);
      *(uint2*)(Op + (size_t)m * 512 + n0 + wc * 64 + lr * 4) = o;
    }
  }
}

// ---------------- combine split-K partials + rowsum-normalize (folded) ------
__global__ __launch_bounds__(256) void combine_norm(const u16* __restrict__ Op,
                                                    const float* __restrict__ rsp,
                                                    u16* __restrict__ ao,
                                                    long spstride, int nsplit, int gi0) {
  const int t = threadIdx.x;
  __shared__ float rinvs[4];
  {
    const int tokl = t >> 6, jg = t & 63;
    float s = rsp[(size_t)jg * NTOK + gi0 + blockIdx.x * 4 + tokl];
    #pragma unroll
    for (int m = 1; m < 64; m <<= 1) s += __shfl_xor(s, m);
    if (jg == 0) rinvs[tokl] = 1.0f / s;
  }
  __syncthreads();
  const size_t idx8 = ((size_t)blockIdx.x * 256 + t) * 8;
  const float ri = rinvs[t >> 6];
  float v[8] = {};
  for (int s = 0; s < nsplit; ++s) {
    const u16* p = Op + (size_t)s * spstride + idx8;
    ushort4 a0 = *(const ushort4*)p;
    ushort4 a1 = *(const ushort4*)(p + 4);
    v[0] += bf2f(a0.x); v[1] += bf2f(a0.y); v[2] += bf2f(a0.z); v[3] += bf2f(a0.w);
    v[4] += bf2f(a1.x); v[5] += bf2f(a1.y); v[6] += bf2f(a1.z); v[7] += bf2f(a1.w);
  }
  uint2 o0, o1;
  o0.x = pk2(v[0] * ri, v[1] * ri);
  o0.y = pk2(v[2] * ri, v[3] * ri);
  o1.x = pk2(v[4] * ri, v[5] * ri);
  o1.y = pk2(v[6] * ri, v[7] * ri);
  *(uint2*)(ao + idx8)     = o0;
  *(uint2*)(ao + idx8 + 4) = o1;
}

// ---------------- proj GEMM (bf16), 128x128 tile + bias + fp32 residual -----
__global__ __launch_bounds__(256, 4) void projgemm_kernel(
    const u16* __restrict__ A, const u16* __restrict__ B,
    const float* __restrict__ bias, const float* __restrict__ resid,
    float* __restrict__ D)
{
  const int z = blockIdx.z;
  B     += (size_t)z * 2097152;
  resid += (size_t)z * 2097152;
  D     += (size_t)z * 2097152;
  const int t = threadIdx.x;
  const int m0 = blockIdx.x * 128, n0 = blockIdx.y * 128;
  const int wv = t >> 6, l = t & 63, lr = l & 15, lq = l >> 4;
  const int wr = wv >> 1, wc = wv & 1;       // 2x2 waves of 64x64
  __shared__ u16 As[128][64];
  __shared__ u16 Bs[128][64];
  f32x4 acc[4][4] = {};
  for (int k0 = 0; k0 < 512; k0 += 64) {
    #pragma unroll
    for (int it = 0; it < 4; ++it) {
      const int ci = it * 256 + t;           // 1024 chunks of 16B
      const int row = ci >> 3;
      const int c8 = (((ci & 7) ^ (row & 7)) << 3);  // inverse-swizzled src octet
      gld_lds16(A + (size_t)(m0 + row) * 512 + k0 + c8, &As[0][0] + ci * 8);
      gld_lds16(B + (size_t)(n0 + row) * 512 + k0 + c8, &Bs[0][0] + ci * 8);
    }
    __syncthreads();
    #pragma unroll
    for (int kk = 0; kk < 64; kk += 32) {
      bf16x8 af[4], bf[4];
      #pragma unroll
      for (int fr = 0; fr < 4; ++fr)
        af[fr] = *(const bf16x8*)swz(&As[0][0], wr * 64 + fr * 16 + lr, kk + lq * 8, 64);
      #pragma unroll
      for (int fc = 0; fc < 4; ++fc)
        bf[fc] = *(const bf16x8*)swz(&Bs[0][0], wc * 64 + fc * 16 + lr, kk + lq * 8, 64);
      #pragma unroll
      for (int fr = 0; fr < 4; ++fr)
        #pragma unroll
        for (int fc = 0; fc < 4; ++fc)
          acc[fr][fc] = MFMA16(af[fr], bf[fc], acc[fr][fc], 0, 0, 0);
    }
    __syncthreads();
  }
  #pragma unroll
  for (int fr = 0; fr < 4; ++fr) {
    #pragma unroll
    for (int reg = 0; reg < 4; ++reg) {
      const int m = m0 + wr * 64 + fr * 16 + lq * 4 + reg;
      const float bm = bias[m];
      #pragma unroll
      for (int fc = 0; fc < 4; ++fc) {
        const int n = n0 + wc * 64 + fc * 16 + lr;
        const size_t idx = (size_t)m * HW_ + n;
        D[idx] = acc[fr][fc][reg] + bm + resid[idx];
      }
    }
  }
}

extern "C" void kernel_launch(void* const* d_in, const int* in_sizes, int n_in,
                              void* d_out, int out_size, void* d_ws, size_t ws_size,
                              hipStream_t stream) {
  const float* x   = (const float*)d_in[0];
  const float* gnw = (const float*)d_in[1];
  const float* gnb = (const float*)d_in[2];
  const float* qw  = (const float*)d_in[3];
  const float* qb  = (const float*)d_in[4];
  const float* kw  = (const float*)d_in[5];
  const float* kb  = (const float*)d_in[6];
  const float* vw  = (const float*)d_in[7];
  const float* vb  = (const float*)d_in[8];
  const float* pw  = (const float*)d_in[9];
  const float* pb  = (const float*)d_in[10];

  // common prefix layout (both modes)
  char* ws = (char*)d_ws;
  u8*    w8    = (u8*)(ws + 0);              // wq|wk fp8 [1024][512B], wv fp8 [512][512B]
  u16*   wpb   = (u16*)(ws + 786432);        // [512][512] bf16, col dim K-permuted
  float* rsp   = (float*)(ws + 2130432);     // [64][8192] f32 (2MB)
  float* gpart = rsp;                        // gn partials alias rsp (pre-sgemm)
  u8*    hT8   = (u8*)(ws + 4227584);        // [8192][512] fp8 (4MB), dead after qkv
  u16*   ao    = (u16*)(ws + 4227584);       // reuse: [2][4096][512] bf16 (8MB, K-perm ch)
  u8*    qk    = (u8*)(ws + 12616192);       // [8192][1024] fp8 (q|k, K-permuted)
  u8*    vm    = (u8*)(ws + 29393408);       // [512][8192] fp8 (K-permuted tokens)

  // big mode: 4-way split-K bf16 Op partials + both-batch fp8 Pexp (R14 map)
  const bool big = ws_size >= 138445312ULL;
  u16* OpB   = (u16*)(ws + 37782016);        // [4][2][4096][512] bf16 (33.5MB)
  u8*  PexpB = (u8*)(ws + 71336448);         // [2][4096][4096] fp8 (33.5MB)
  // fallback (ws >= 77.66MB proven): single-batch fp8 Pexp + 2-way Op
  u8*  PexpS = (u8*)(ws + 37782016);         // [4096][4096] fp8 (16.8MB)
  u16* OpS   = (u16*)(ws + 54559232);        // [2][4096][512] bf16 (8MB)

  head_kernel<<<1536, 256, 0, stream>>>(qw, kw, vw, pw, w8, wpb, x, gpart);
  gn_apply_kernel<<<dim3(64, 8, 2), 256, 0, stream>>>(x, gnw, gnb, gpart, hT8);
  // merged q+k (512 blocks) and v (256 blocks) in one dispatch
  qkv_kernel<<<768, 256, 0, stream>>>(hT8, w8, qb, kb, vb, qk, vm);

  if (big) {
    sgemm_exp_kernel<<<dim3(32, 32, 2), 256, 0, stream>>>(qk, qk + 512, PexpB, rsp, PZ_, 0);
    pvgemm_splitk<<<dim3(32, 4, 8), 256, 0, stream>>>(PexpB, vm, OpB, 4194304L, 2);
    combine_norm<<<2048, 256, 0, stream>>>(OpB, rsp, ao, 4194304L, 4, 0);
  } else {
    for (int b = 0; b < 2; ++b) {
      const u8* qkb = qk + (size_t)b * HW_ * 1024;
      sgemm_exp_kernel<<<dim3(32, 32, 1), 256, 0, stream>>>(qkb, qkb + 512, PexpS, rsp, 0L, b * HW_);
      pvgemm_splitk<<<dim3(32, 4, 2), 256, 0, stream>>>(PexpS, vm + (size_t)b * HW_, OpS, 2097152L, 1);
      combine_norm<<<1024, 256, 0, stream>>>(OpS, rsp, ao + (size_t)b * HW_ * C_, 2097152L, 2, b * HW_);
    }
  }
  // proj + bias + residual: A=wpb (cols K-permuted), B=ao (cols K-permuted)
  projgemm_kernel<<<dim3(4, 32, 2), 256, 0, stream>>>(wpb, ao, pb, x, (float*)d_out);
}

// Round 17
// 112.125 us; speedup vs baseline: 6.2687x; 1.0503x over previous
//
#include <hip/hip_runtime.h>
#include <hip/hip_bf16.h>

#define C_   512
#define HW_  4096
#define NTOK 8192
#define PZ_  16777216L   // Pexp batch stride (BYTES, fp8) in big mode

typedef __attribute__((ext_vector_type(8))) short bf16x8;
typedef __attribute__((ext_vector_type(4))) float f32x4;
typedef unsigned short u16;
typedef unsigned char u8;
typedef long i64;

#define MFMA16 __builtin_amdgcn_mfma_f32_16x16x32_bf16
#define MFMA8  __builtin_amdgcn_mfma_f32_16x16x32_fp8_fp8

__device__ __forceinline__ u16 f2bf(float f) {
  unsigned int u = __float_as_uint(f);
  u += 0x7fffu + ((u >> 16) & 1u);
  return (u16)(u >> 16);
}

// hardware packed f32->bf16 RNE (v_cvt_pk_bf16_f32)
__device__ __forceinline__ unsigned pk2(float a, float b) {
  __hip_bfloat162 h = __float22bfloat162_rn(make_float2(a, b));
  return *reinterpret_cast<unsigned*>(&h);
}

// hardware packed f32->fp8 e4m3 (v_cvt_pk_fp8_f32), 4 values -> u32
__device__ __forceinline__ unsigned pk4f8(float a, float b, float c, float d) {
  unsigned r = __builtin_amdgcn_cvt_pk_fp8_f32(a, b, 0u, false);
  return __builtin_amdgcn_cvt_pk_fp8_f32(c, d, r, true);
}

__device__ __forceinline__ float bf2f(u16 v) {
  return __uint_as_float((unsigned)v << 16);
}

__device__ __forceinline__ void gld_lds16(const void* g, void* l) {
  __builtin_amdgcn_global_load_lds(
      (const __attribute__((address_space(1))) void*)g,
      (__attribute__((address_space(3))) void*)l, 16, 0, 0);
}

// bf16 LDS swizzle (128-B rows, 8 chunks of 16B): chunk ^= row&7
__device__ __forceinline__ const u16* swz(const u16* base, int row, int col, int ldu16) {
  return base + (size_t)row * ldu16 + ((((col >> 3) ^ (row & 7)) << 3) | (col & 7));
}

// fp8 LDS tile [128 rows][128 B] (BK=128), 8 chunks of 16B/row: chunk ^= row&7.
// Fragment for (row, K-slice h=0..3, lq): logical byte = h*32 + lq*8 ->
// logical chunk h*2+(lq>>1), within (lq&1)*8. b64 read: 16 lanes -> 8 chunks
// x 2 lanes sharing the same 8B range = 2-way = free (m136). R16's 64-B rows
// were a 4-way conflict (4.2M SQ_LDS_BANK_CONFLICT) -- this fixes it.
__device__ __forceinline__ const i64* swz8w(const u8* base, int row, int h, int lq) {
  const int chunk = (h * 2 + (lq >> 1)) ^ (row & 7);
  return (const i64*)(base + row * 128 + (chunk << 4) + (lq & 1) * 8);
}

// K-PERMUTED STORAGE (within each 64-wide K group, logical col g*64+f*16+r
// stored at g*64+r*4+f). Consumers pair operands positionally -> MFMA
// k-reductions unaffected. Applied to qk/Pexp/vm (fp8), Op/ao/wpb (bf16).
// hT8 / weight K-dims are written in NATURAL order (both sides natural).
//
// LAUNCH_BOUNDS NOTE (R15 post-mortem): acc[4][4] = 64 AGPRs counts against
// the unified VGPR file; (256,8)'s 64-reg cap forced scratch spill (10x).
// Keep (256,4) = 128-reg cap on all 128^2 GEMMs.

// ---------------- head: wcast (bid<1024) + gn_stats1 (bid>=1024) ------------
__global__ __launch_bounds__(256) void head_kernel(
    const float* __restrict__ qw, const float* __restrict__ kw,
    const float* __restrict__ vw, const float* __restrict__ pw,
    u8* __restrict__ w8, u16* __restrict__ wpb, const float* __restrict__ x,
    float* __restrict__ gpart) {
  const int bid = blockIdx.x;
  const int t = threadIdx.x;
  if (bid < 1024) {
    int gid = bid * 256 + t;
    int which = gid >> 16;
    const float* src = which == 0 ? qw : which == 1 ? kw : which == 2 ? vw : pw;
    int loc = (gid & 65535) * 4;
    float4 v = *(const float4*)(src + loc);
    if (which == 3) {
      // wpb: bf16, permute channel (col) dim to match ao's stored layout
      const int row = loc >> 9, c = loc & 511;
      const int g = c & ~63, f = (c >> 4) & 3, r0 = c & 15;
      u16* base = wpb + (size_t)row * 512 + g;
      base[(r0 + 0) * 4 + f] = f2bf(v.x);
      base[(r0 + 1) * 4 + f] = f2bf(v.y);
      base[(r0 + 2) * 4 + f] = f2bf(v.z);
      base[(r0 + 3) * 4 + f] = f2bf(v.w);
    } else {
      // wq/wk/wv: fp8, natural K order
      *(unsigned*)(w8 + (size_t)which * 262144 + loc) = pk4f8(v.x, v.y, v.z, v.w);
    }
    return;
  }
  const int gb = bid - 1024;          // 512 blocks: group = gb>>3, chunk = gb&7
  const float4* p = (const float4*)(x + (size_t)(gb >> 3) * 65536 + (gb & 7) * 8192);
  float s = 0.0f, ss = 0.0f;
  for (int i = t; i < 2048; i += 256) {
    float4 v = p[i];
    s  += v.x + v.y + v.z + v.w;
    ss += v.x * v.x + v.y * v.y + v.z * v.z + v.w * v.w;
  }
  #pragma unroll
  for (int m = 1; m < 64; m <<= 1) { s += __shfl_xor(s, m); ss += __shfl_xor(ss, m); }
  __shared__ float rs[4], rss[4];
  const int wv = t >> 6;
  if ((t & 63) == 0) { rs[wv] = s; rss[wv] = ss; }
  __syncthreads();
  if (t == 0) {
    gpart[gb * 2]     = rs[0] + rs[1] + rs[2] + rs[3];
    gpart[gb * 2 + 1] = rss[0] + rss[1] + rss[2] + rss[3];
  }
}

// ---------------- GN apply (stage2 folded) + transpose to hT8[8192][512] fp8 -
__global__ __launch_bounds__(256) void gn_apply_kernel(const float* __restrict__ x,
                                                       const float* __restrict__ gnw,
                                                       const float* __restrict__ gnb,
                                                       const float* __restrict__ gpart,
                                                       u8* __restrict__ hT8) {
  const int b = blockIdx.z, c0 = blockIdx.y * 64, hw0 = blockIdx.x * 64;
  const int t = threadIdx.x;
  __shared__ float tile[64][65];
  __shared__ float gmean[4], grstd[4];
  if (t < 4) {
    const int g = b * 32 + (c0 >> 4) + t;
    float s = 0.0f, ss = 0.0f;
    #pragma unroll
    for (int cch = 0; cch < 8; ++cch) {
      s  += gpart[(g * 8 + cch) * 2];
      ss += gpart[(g * 8 + cch) * 2 + 1];
    }
    float mean = s * (1.0f / 65536.0f);
    float var  = fmaxf(ss * (1.0f / 65536.0f) - mean * mean, 0.0f);
    gmean[t] = mean;
    grstd[t] = rsqrtf(var + 1e-6f);
  }
  __syncthreads();
  {
    const int tx = t & 63, ty = t >> 6;  // ty 0..3
    #pragma unroll
    for (int i = 0; i < 16; ++i) {
      int cl = ty * 16 + i;
      int c = c0 + cl;
      float val = x[((size_t)(b * C_ + c)) * HW_ + hw0 + tx];
      tile[cl][tx] = (val - gmean[cl >> 4]) * grstd[cl >> 4] * gnw[c] + gnb[c];
    }
  }
  __syncthreads();
  {
    const int cx = (t & 15) * 4, ty = t >> 4;  // ty 0..15, 4 channels/thread
    #pragma unroll
    for (int i = 0; i < 4; ++i) {
      int hwl = ty * 4 + i;
      *(unsigned*)&hT8[((size_t)(b * HW_ + hw0 + hwl)) * 512 + c0 + cx] =
          pk4f8(tile[cx][hwl], tile[cx + 1][hwl], tile[cx + 2][hwl], tile[cx + 3][hwl]);
    }
  }
}

// ---------------- merged QKV GEMM (fp8 in), fp8 K-permuted out --------------
// bid < 512: qk part -> qk[8192][1024] fp8. bid >= 512: v -> vm[512][8192] fp8.
// BK=128 fp8 tiles: [128][128B], conflict-free swizzle.
__global__ __launch_bounds__(256, 4) void qkv_kernel(
    const u8* __restrict__ hT8, const u8* __restrict__ w8,
    const float* __restrict__ qb, const float* __restrict__ kb,
    const float* __restrict__ vb,
    u8* __restrict__ qk, u8* __restrict__ vm)
{
  const int bid = blockIdx.x;
  const int t = threadIdx.x;
  const int wv = t >> 6, l = t & 63, lr = l & 15, lq = l >> 4;
  const int wr = wv >> 1, wc = wv & 1;       // 2x2 waves of 64x64
  const bool isqk = bid < 512;
  const int m0 = isqk ? (bid >> 3) * 128 : ((bid - 512) >> 6) * 128;
  const int n0 = isqk ? (bid & 7) * 128  : ((bid - 512) & 63) * 128;
  const u8* Arow = (isqk ? hT8 : w8 + 524288) + (size_t)m0 * 512;
  const u8* Brow = (isqk ? w8 : hT8) + (size_t)n0 * 512;
  __shared__ u8 As[16384];                   // [128][128B], chunk ^= row&7
  __shared__ u8 Bs[16384];
  f32x4 acc[4][4] = {};
  for (int k0 = 0; k0 < 512; k0 += 128) {
    #pragma unroll
    for (int it = 0; it < 4; ++it) {
      const int ci = it * 256 + t;           // 1024 chunks of 16B per tile
      const int row = ci >> 3;
      const int src = (((ci & 7) ^ (row & 7)) << 4);  // inverse-swizzled octet
      gld_lds16(Arow + (size_t)row * 512 + k0 + src, As + ci * 16);
      gld_lds16(Brow + (size_t)row * 512 + k0 + src, Bs + ci * 16);
    }
    __syncthreads();
    #pragma unroll
    for (int h = 0; h < 4; ++h) {
      i64 af[4], bf[4];
      #pragma unroll
      for (int fr = 0; fr < 4; ++fr)
        af[fr] = *swz8w(As, wr * 64 + fr * 16 + lr, h, lq);
      #pragma unroll
      for (int fc = 0; fc < 4; ++fc)
        bf[fc] = *swz8w(Bs, wc * 64 + fc * 16 + lr, h, lq);
      #pragma unroll
      for (int fr = 0; fr < 4; ++fr)
        #pragma unroll
        for (int fc = 0; fc < 4; ++fc)
          acc[fr][fc] = MFMA8(af[fr], bf[fc], acc[fr][fc], 0, 0, 0);
    }
    __syncthreads();
  }
  if (isqk) {
    float bn[4];
    #pragma unroll
    for (int fc = 0; fc < 4; ++fc) {
      const int n = n0 + wc * 64 + fc * 16 + lr;     // logical col for bias
      bn[fc] = n < 512 ? qb[n] : kb[n - 512];
    }
    #pragma unroll
    for (int fr = 0; fr < 4; ++fr) {
      #pragma unroll
      for (int reg = 0; reg < 4; ++reg) {
        const int m = m0 + wr * 64 + fr * 16 + lq * 4 + reg;
        *(unsigned*)(qk + (size_t)m * 1024 + n0 + wc * 64 + lr * 4) =
            pk4f8(acc[fr][0][reg] + bn[0], acc[fr][1][reg] + bn[1],
                  acc[fr][2][reg] + bn[2], acc[fr][3][reg] + bn[3]);
      }
    }
  } else {
    #pragma unroll
    for (int fr = 0; fr < 4; ++fr) {
      #pragma unroll
      for (int reg = 0; reg < 4; ++reg) {
        const int m = m0 + wr * 64 + fr * 16 + lq * 4 + reg;
        const float bm = vb[m];
        *(unsigned*)(vm + (size_t)m * NTOK + n0 + wc * 64 + lr * 4) =
            pk4f8(acc[fr][0][reg] + bm, acc[fr][1][reg] + bm,
                  acc[fr][2][reg] + bm, acc[fr][3][reg] + bm);
      }
    }
  }
}

// ---------------- S-GEMM fp8 + exp + rowsum partials -------------------------
// A,B = qk fp8 slices (row stride 1024 B). Pexp fp8, K-permuted cols. BK=128.
__global__ __launch_bounds__(256, 4) void sgemm_exp_kernel(
    const u8* __restrict__ A, const u8* __restrict__ B,
    u8* __restrict__ Pexp, float* __restrict__ rsp, long pz, int gi0base)
{
  const int z = blockIdx.z;
  A    += (size_t)z * (HW_ * 1024);
  B    += (size_t)z * (HW_ * 1024);
  Pexp += (size_t)z * pz;
  const int gi0 = gi0base + z * HW_;
  const int t = threadIdx.x;
  const int m0 = blockIdx.x * 128, n0 = blockIdx.y * 128;
  const int wv = t >> 6, l = t & 63, lr = l & 15, lq = l >> 4;
  const int wr = wv >> 1, wc = wv & 1;       // 2x2 waves of 64x64
  __shared__ u8 As[16384];                   // [128][128B], chunk ^= row&7
  __shared__ u8 Bs[16384];
  f32x4 acc[4][4] = {};
  for (int k0 = 0; k0 < 512; k0 += 128) {
    #pragma unroll
    for (int it = 0; it < 4; ++it) {
      const int ci = it * 256 + t;           // 1024 chunks of 16B per tile
      const int row = ci >> 3;
      const int src = (((ci & 7) ^ (row & 7)) << 4);
      gld_lds16(A + (size_t)(m0 + row) * 1024 + k0 + src, As + ci * 16);
      gld_lds16(B + (size_t)(n0 + row) * 1024 + k0 + src, Bs + ci * 16);
    }
    __syncthreads();
    #pragma unroll
    for (int h = 0; h < 4; ++h) {
      i64 af[4], bf[4];
      #pragma unroll
      for (int fr = 0; fr < 4; ++fr)
        af[fr] = *swz8w(As, wr * 64 + fr * 16 + lr, h, lq);
      #pragma unroll
      for (int fc = 0; fc < 4; ++fc)
        bf[fc] = *swz8w(Bs, wc * 64 + fc * 16 + lr, h, lq);
      #pragma unroll
      for (int fr = 0; fr < 4; ++fr)
        #pragma unroll
        for (int fc = 0; fc < 4; ++fc)
          acc[fr][fc] = MFMA8(af[fr], bf[fc], acc[fr][fc], 0, 0, 0);
    }
    __syncthreads();
  }
  const float SCL2 = 0.06376774487989831f;   // log2(e)/sqrt(512)
  #pragma unroll
  for (int fr = 0; fr < 4; ++fr) {
    #pragma unroll
    for (int reg = 0; reg < 4; ++reg) {
      const int row = m0 + wr * 64 + fr * 16 + lq * 4 + reg;
      float p0 = exp2f(acc[fr][0][reg] * SCL2 - 1.0f);
      float p1 = exp2f(acc[fr][1][reg] * SCL2 - 1.0f);
      float p2 = exp2f(acc[fr][2][reg] * SCL2 - 1.0f);
      float p3 = exp2f(acc[fr][3][reg] * SCL2 - 1.0f);
      float rsum = p0 + p1 + p2 + p3;
      *(unsigned*)(Pexp + (size_t)row * 4096 + n0 + wc * 64 + lr * 4) =
          pk4f8(p0, p1, p2, p3);
      rsum += __shfl_xor(rsum, 1);
      rsum += __shfl_xor(rsum, 2);
      rsum += __shfl_xor(rsum, 4);
      rsum += __shfl_xor(rsum, 8);
      if (lr == 0)
        rsp[(size_t)(blockIdx.y * 2 + wc) * NTOK + gi0 + row] = rsum;
    }
  }
}

// ---------------- PV GEMM fp8 split-K, 128x128 tile, BK=128 -----------------
// A=Pexp fp8 (row 4096 B), B=vm fp8 (row 8192 B). Op bf16, K-permuted ch.
__global__ __launch_bounds__(256, 4) void pvgemm_splitk(
    const u8* __restrict__ A, const u8* __restrict__ B,
    u16* __restrict__ Op, long spstride, int logsplit)
{
  const int z = blockIdx.z;
  const int sp = z & ((1 << logsplit) - 1);
  const int bb = z >> logsplit;
  A  += (size_t)bb * PZ_;
  B  += (size_t)bb * HW_;
  Op += (size_t)sp * spstride + (size_t)bb * 2097152;
  const int t = threadIdx.x;
  const int m0 = blockIdx.x * 128, n0 = blockIdx.y * 128;
  const int wv = t >> 6, l = t & 63, lr = l & 15, lq = l >> 4;
  const int wr = wv >> 1, wc = wv & 1;       // 2x2 waves of 64x64
  __shared__ u8 As[16384];
  __shared__ u8 Bs[16384];
  f32x4 acc[4][4] = {};
  const int ksize = 4096 >> logsplit;
  const int kbeg = sp * ksize;
  for (int k0 = kbeg; k0 < kbeg + ksize; k0 += 128) {
    #pragma unroll
    for (int it = 0; it < 4; ++it) {
      const int ci = it * 256 + t;           // 1024 chunks per tile
      const int row = ci >> 3;
      const int src = (((ci & 7) ^ (row & 7)) << 4);
      gld_lds16(A + (size_t)(m0 + row) * 4096 + k0 + src, As + ci * 16);
      gld_lds16(B + (size_t)(n0 + row) * NTOK + k0 + src, Bs + ci * 16);
    }
    __syncthreads();
    #pragma unroll
    for (int h = 0; h < 4; ++h) {
      i64 af[4], bf[4];
      #pragma unroll
      for (int fr = 0; fr < 4; ++fr)
        af[fr] = *swz8w(As, wr * 64 + fr * 16 + lr, h, lq);
      #pragma unroll
      for (int fc = 0; fc < 4; ++fc)
        bf[fc] = *swz8w(Bs, wc * 64 + fc * 16 + lr, h, lq);
      #pragma unroll
      for (int fr = 0; fr < 4; ++fr)
        #pragma unroll
        for (int fc = 0; fc < 4; ++fc)
          acc[fr][fc] = MFMA8(af[fr], bf[fc], acc[fr][fc], 0, 0, 0);
    }
    __syncthreads();
  }
  #pragma unroll
  for (int fr = 0; fr < 4; ++fr) {
    #pragma unroll
    for (int reg = 0; reg < 4; ++reg) {
      const int m = m0 + wr * 64 + fr * 16 + lq * 4 + reg;
      uint2 o;
      o.x = pk2(acc[fr][0][reg], acc[fr][1][reg]);
      o.y = pk2(acc[fr][2][reg], acc[fr][3][reg]);
      *(uint2*)(Op + (size_t)m * 512 + n0 + wc * 64 + lr * 4) = o;
    }
  }
}

// ---------------- combine split-K partials + rowsum-normalize (folded) ------
__global__ __launch_bounds__(256) void combine_norm(const u16* __restrict__ Op,
                                                    const float* __restrict__ rsp,
                                                    u16* __restrict__ ao,
                                                    long spstride, int nsplit, int gi0) {
  const int t = threadIdx.x;
  __shared__ float rinvs[4];
  {
    const int tokl = t >> 6, jg = t & 63;
    float s = rsp[(size_t)jg * NTOK + gi0 + blockIdx.x * 4 + tokl];
    #pragma unroll
    for (int m = 1; m < 64; m <<= 1) s += __shfl_xor(s, m);
    if (jg == 0) rinvs[tokl] = 1.0f / s;
  }
  __syncthreads();
  const size_t idx8 = ((size_t)blockIdx.x * 256 + t) * 8;
  const float ri = rinvs[t >> 6];
  float v[8] = {};
  for (int s = 0; s < nsplit; ++s) {
    const u16* p = Op + (size_t)s * spstride + idx8;
    ushort4 a0 = *(const ushort4*)p;
    ushort4 a1 = *(const ushort4*)(p + 4);
    v[0] += bf2f(a0.x); v[1] += bf2f(a0.y); v[2] += bf2f(a0.z); v[3] += bf2f(a0.w);
    v[4] += bf2f(a1.x); v[5] += bf2f(a1.y); v[6] += bf2f(a1.z); v[7] += bf2f(a1.w);
  }
  uint2 o0, o1;
  o0.x = pk2(v[0] * ri, v[1] * ri);
  o0.y = pk2(v[2] * ri, v[3] * ri);
  o1.x = pk2(v[4] * ri, v[5] * ri);
  o1.y = pk2(v[6] * ri, v[7] * ri);
  *(uint2*)(ao + idx8)     = o0;
  *(uint2*)(ao + idx8 + 4) = o1;
}

// ---------------- proj GEMM (bf16), 128x128 tile + bias + fp32 residual -----
__global__ __launch_bounds__(256, 4) void projgemm_kernel(
    const u16* __restrict__ A, const u16* __restrict__ B,
    const float* __restrict__ bias, const float* __restrict__ resid,
    float* __restrict__ D)
{
  const int z = blockIdx.z;
  B     += (size_t)z * 2097152;
  resid += (size_t)z * 2097152;
  D     += (size_t)z * 2097152;
  const int t = threadIdx.x;
  const int m0 = blockIdx.x * 128, n0 = blockIdx.y * 128;
  const int wv = t >> 6, l = t & 63, lr = l & 15, lq = l >> 4;
  const int wr = wv >> 1, wc = wv & 1;       // 2x2 waves of 64x64
  __shared__ u16 As[128][64];
  __shared__ u16 Bs[128][64];
  f32x4 acc[4][4] = {};
  for (int k0 = 0; k0 < 512; k0 += 64) {
    #pragma unroll
    for (int it = 0; it < 4; ++it) {
      const int ci = it * 256 + t;           // 1024 chunks of 16B
      const int row = ci >> 3;
      const int c8 = (((ci & 7) ^ (row & 7)) << 3);  // inverse-swizzled src octet
      gld_lds16(A + (size_t)(m0 + row) * 512 + k0 + c8, &As[0][0] + ci * 8);
      gld_lds16(B + (size_t)(n0 + row) * 512 + k0 + c8, &Bs[0][0] + ci * 8);
    }
    __syncthreads();
    #pragma unroll
    for (int kk = 0; kk < 64; kk += 32) {
      bf16x8 af[4], bf[4];
      #pragma unroll
      for (int fr = 0; fr < 4; ++fr)
        af[fr] = *(const bf16x8*)swz(&As[0][0], wr * 64 + fr * 16 + lr, kk + lq * 8, 64);
      #pragma unroll
      for (int fc = 0; fc < 4; ++fc)
        bf[fc] = *(const bf16x8*)swz(&Bs[0][0], wc * 64 + fc * 16 + lr, kk + lq * 8, 64);
      #pragma unroll
      for (int fr = 0; fr < 4; ++fr)
        #pragma unroll
        for (int fc = 0; fc < 4; ++fc)
          acc[fr][fc] = MFMA16(af[fr], bf[fc], acc[fr][fc], 0, 0, 0);
    }
    __syncthreads();
  }
  #pragma unroll
  for (int fr = 0; fr < 4; ++fr) {
    #pragma unroll
    for (int reg = 0; reg < 4; ++reg) {
      const int m = m0 + wr * 64 + fr * 16 + lq * 4 + reg;
      const float bm = bias[m];
      #pragma unroll
      for (int fc = 0; fc < 4; ++fc) {
        const int n = n0 + wc * 64 + fc * 16 + lr;
        const size_t idx = (size_t)m * HW_ + n;
        D[idx] = acc[fr][fc][reg] + bm + resid[idx];
      }
    }
  }
}

extern "C" void kernel_launch(void* const* d_in, const int* in_sizes, int n_in,
                              void* d_out, int out_size, void* d_ws, size_t ws_size,
                              hipStream_t stream) {
  const float* x   = (const float*)d_in[0];
  const float* gnw = (const float*)d_in[1];
  const float* gnb = (const float*)d_in[2];
  const float* qw  = (const float*)d_in[3];
  const float* qb  = (const float*)d_in[4];
  const float* kw  = (const float*)d_in[5];
  const float* kb  = (const float*)d_in[6];
  const float* vw  = (const float*)d_in[7];
  const float* vb  = (const float*)d_in[8];
  const float* pw  = (const float*)d_in[9];
  const float* pb  = (const float*)d_in[10];

  // common prefix layout (both modes)
  char* ws = (char*)d_ws;
  u8*    w8    = (u8*)(ws + 0);              // wq|wk fp8 [1024][512B], wv fp8 [512][512B]
  u16*   wpb   = (u16*)(ws + 786432);        // [512][512] bf16, col dim K-permuted
  float* rsp   = (float*)(ws + 2130432);     // [64][8192] f32 (2MB)
  float* gpart = rsp;                        // gn partials alias rsp (pre-sgemm)
  u8*    hT8   = (u8*)(ws + 4227584);        // [8192][512] fp8 (4MB), dead after qkv
  u16*   ao    = (u16*)(ws + 4227584);       // reuse: [2][4096][512] bf16 (8MB, K-perm ch)
  u8*    qk    = (u8*)(ws + 12616192);       // [8192][1024] fp8 (q|k, K-permuted)
  u8*    vm    = (u8*)(ws + 29393408);       // [512][8192] fp8 (K-permuted tokens)

  // big mode: 4-way split-K bf16 Op partials + both-batch fp8 Pexp
  const bool big = ws_size >= 138445312ULL;
  u16* OpB   = (u16*)(ws + 37782016);        // [4][2][4096][512] bf16 (33.5MB)
  u8*  PexpB = (u8*)(ws + 71336448);         // [2][4096][4096] fp8 (33.5MB)
  // fallback (ws >= 77.66MB proven): single-batch fp8 Pexp + 2-way Op
  u8*  PexpS = (u8*)(ws + 37782016);         // [4096][4096] fp8 (16.8MB)
  u16* OpS   = (u16*)(ws + 54559232);        // [2][4096][512] bf16 (8MB)

  head_kernel<<<1536, 256, 0, stream>>>(qw, kw, vw, pw, w8, wpb, x, gpart);
  gn_apply_kernel<<<dim3(64, 8, 2), 256, 0, stream>>>(x, gnw, gnb, gpart, hT8);
  // merged q+k (512 blocks) and v (256 blocks) in one dispatch
  qkv_kernel<<<768, 256, 0, stream>>>(hT8, w8, qb, kb, vb, qk, vm);

  if (big) {
    sgemm_exp_kernel<<<dim3(32, 32, 2), 256, 0, stream>>>(qk, qk + 512, PexpB, rsp, PZ_, 0);
    pvgemm_splitk<<<dim3(32, 4, 8), 256, 0, stream>>>(PexpB, vm, OpB, 4194304L, 2);
    combine_norm<<<2048, 256, 0, stream>>>(OpB, rsp, ao, 4194304L, 4, 0);
  } else {
    for (int b = 0; b < 2; ++b) {
      const u8* qkb = qk + (size_t)b * HW_ * 1024;
      sgemm_exp_kernel<<<dim3(32, 32, 1), 256, 0, stream>>>(qkb, qkb + 512, PexpS, rsp, 0L, b * HW_);
      pvgemm_splitk<<<dim3(32, 4, 2), 256, 0, stream>>>(PexpS, vm + (size_t)b * HW_, OpS, 2097152L, 1);
      combine_norm<<<1024, 256, 0, stream>>>(OpS, rsp, ao + (size_t)b * HW_ * C_, 2097152L, 2, b * HW_);
    }
  }
  // proj + bias + residual: A=wpb (cols K-permuted), B=ao (cols K-permuted)
  projgemm_kernel<<<dim3(4, 32, 2), 256, 0, stream>>>(wpb, ao, pb, x, (float*)d_out);
}